// Round 3
// baseline (355.961 us; speedup 1.0000x reference)
//
#include <hip/hip_runtime.h>
#include <math.h>

#define NPOS 2048   // n
#define MFFT 4096   // 2n
#define NH 8        // heads
#define PDW 16      // pos_dim
#define NE 64       // E
#define NB 16       // batch

__device__ __forceinline__ float2 cmul(float2 a, float2 b) {
    return make_float2(a.x * b.x - a.y * b.y, a.x * b.y + a.y * b.x);
}

#define C16_1 0.92387953251128674f
#define S16_1 0.38268343236508978f
#define C16_2 0.70710678118654757f

// 16-point DFT in registers, natural order in -> natural order out.
// SGN=-1: forward (e^{-2pi i nk/16}); SGN=+1: inverse (no 1/16 scaling).
template <int SGN>
__device__ __forceinline__ void dft16(float2 v[16]) {
    float2 y[16];
    // stage A: DFT4 over n2 (elements n1 + 4*n2), result k2 -> y[n1 + 4*k2]
    #pragma unroll
    for (int n1 = 0; n1 < 4; ++n1) {
        float2 a = v[n1], b = v[n1 + 4], c = v[n1 + 8], d = v[n1 + 12];
        float2 s02 = make_float2(a.x + c.x, a.y + c.y);
        float2 d02 = make_float2(a.x - c.x, a.y - c.y);
        float2 s13 = make_float2(b.x + d.x, b.y + d.y);
        float2 d13 = make_float2(b.x - d.x, b.y - d.y);
        float2 rot = (SGN < 0) ? make_float2(d13.y, -d13.x)   // -i * d13
                               : make_float2(-d13.y, d13.x);  // +i * d13
        y[n1]      = make_float2(s02.x + s13.x, s02.y + s13.y);
        y[n1 + 4]  = make_float2(d02.x + rot.x, d02.y + rot.y);
        y[n1 + 8]  = make_float2(s02.x - s13.x, s02.y - s13.y);
        y[n1 + 12] = make_float2(d02.x - rot.x, d02.y - rot.y);
    }
    // twiddles W16^{n1*k2} (conj for inverse)
    const float sg = (SGN < 0) ? -1.f : 1.f;
    const float2 W1 = make_float2(C16_1, sg * S16_1);
    const float2 W2 = make_float2(C16_2, sg * C16_2);
    const float2 W3 = make_float2(S16_1, sg * C16_1);
    const float2 W6 = make_float2(-C16_2, sg * C16_2);
    const float2 W9 = make_float2(-C16_1, -sg * S16_1);
    y[5]  = cmul(y[5],  W1);   // (n1=1,k2=1)
    y[9]  = cmul(y[9],  W2);   // (1,2)
    y[13] = cmul(y[13], W3);   // (1,3)
    y[6]  = cmul(y[6],  W2);   // (2,1)
    y[10] = (SGN < 0) ? make_float2(y[10].y, -y[10].x)        // (2,2): *W16^4 = -i
                      : make_float2(-y[10].y, y[10].x);
    y[14] = cmul(y[14], W6);   // (2,3)
    y[7]  = cmul(y[7],  W3);   // (3,1)
    y[11] = cmul(y[11], W6);   // (3,2)
    y[15] = cmul(y[15], W9);   // (3,3)
    // stage B: DFT4 over n1 (elements y[4*k2 + n1]), result k1 -> v[4*k1 + k2]
    #pragma unroll
    for (int k2 = 0; k2 < 4; ++k2) {
        float2 a = y[4 * k2], b = y[4 * k2 + 1], c = y[4 * k2 + 2], d = y[4 * k2 + 3];
        float2 s02 = make_float2(a.x + c.x, a.y + c.y);
        float2 d02 = make_float2(a.x - c.x, a.y - c.y);
        float2 s13 = make_float2(b.x + d.x, b.y + d.y);
        float2 d13 = make_float2(b.x - d.x, b.y - d.y);
        float2 rot = (SGN < 0) ? make_float2(d13.y, -d13.x)
                               : make_float2(-d13.y, d13.x);
        v[k2]      = make_float2(s02.x + s13.x, s02.y + s13.y);
        v[4 + k2]  = make_float2(d02.x + rot.x, d02.y + rot.y);
        v[8 + k2]  = make_float2(s02.x - s13.x, s02.y - s13.y);
        v[12 + k2] = make_float2(d02.x - rot.x, d02.y - rot.y);
    }
}

// 4096-pt FFT: 3 radix-16 register stages, 2 swizzled LDS transposes, 2 barriers.
// Input: v[q] = x[tid + 256 q] (natural). Output: v[k] = bin pi(16 tid + k)
// for a fixed digit-reversal pi (cancelled by fft4096_inv / matched by V).
// LDS swizzle: addr(p) = p ^ ((p>>4)&15)  -> all patterns at b64 bank floor.
__device__ __forceinline__ void fft4096_fwd(float2 v[16], float2* sh, int tid) {
    dft16<-1>(v);
    {
        float2 w1; __sincosf(-1.5339807878856412e-3f * (float)tid, &w1.y, &w1.x); // -2pi/4096 * tid
        int tA = tid ^ (tid >> 4);
        sh[tA] = v[0];
        float2 tw = w1;
        #pragma unroll
        for (int k = 1; k < 16; ++k) {
            v[k] = cmul(v[k], tw);
            sh[tA + 256 * k] = v[k];
            tw = cmul(tw, w1);
        }
    }
    __syncthreads();
    int t2 = tid & 15, bb = tid >> 4, baseB = bb * 256;
    #pragma unroll
    for (int k = 0; k < 16; ++k) v[k] = sh[baseB + 16 * k + (t2 ^ k)];
    dft16<-1>(v);
    {
        float2 w1; __sincosf(-2.4543692606170259e-2f * (float)t2, &w1.y, &w1.x); // -2pi/256 * t2
        sh[baseB + t2] = v[0];
        float2 tw = w1;
        #pragma unroll
        for (int k = 1; k < 16; ++k) {
            v[k] = cmul(v[k], tw);
            sh[baseB + 16 * k + (t2 ^ k)] = v[k];
            tw = cmul(tw, w1);
        }
    }
    __syncthreads();
    int tC = tid & 15;
    #pragma unroll
    for (int q = 0; q < 16; ++q) v[q] = sh[16 * tid + (q ^ tC)];
    dft16<-1>(v);
}

// Exact step-mirror of fft4096_fwd. Input: register layout produced by fwd.
// Output: v[q] = x[tid + 256 q] natural. No 1/M scaling (folded into V).
__device__ __forceinline__ void fft4096_inv(float2 v[16], float2* sh, int tid) {
    dft16<1>(v);
    int tC = tid & 15;
    #pragma unroll
    for (int q = 0; q < 16; ++q) sh[16 * tid + (q ^ tC)] = v[q];
    __syncthreads();
    int t2 = tid & 15, bb = tid >> 4, baseB = bb * 256;
    #pragma unroll
    for (int k = 0; k < 16; ++k) v[k] = sh[baseB + 16 * k + (t2 ^ k)];
    {
        float2 w1; __sincosf(2.4543692606170259e-2f * (float)t2, &w1.y, &w1.x);
        float2 tw = w1;
        #pragma unroll
        for (int k = 1; k < 16; ++k) { v[k] = cmul(v[k], tw); tw = cmul(tw, w1); }
    }
    dft16<1>(v);
    #pragma unroll
    for (int q = 0; q < 16; ++q) sh[baseB + 16 * q + (t2 ^ q)] = v[q];
    __syncthreads();
    int tA = tid ^ (tid >> 4);
    #pragma unroll
    for (int k = 0; k < 16; ++k) v[k] = sh[tA + 256 * k];
    {
        float2 w1; __sincosf(1.5339807878856412e-3f * (float)tid, &w1.y, &w1.x);
        float2 tw = w1;
        #pragma unroll
        for (int k = 1; k < 16; ++k) { v[k] = cmul(v[k], tw); tw = cmul(tw, w1); }
    }
    dft16<1>(v);
}

#define LN_RELU(G, Bv)                                                        \
    {                                                                         \
        float mu = 0.f;                                                       \
        _Pragma("unroll") for (int i = 0; i < PDW; ++i) mu += h[i];           \
        mu *= (1.0f / PDW);                                                   \
        float var = 0.f;                                                      \
        _Pragma("unroll") for (int i = 0; i < PDW; ++i) {                     \
            float d = h[i] - mu;                                              \
            var += d * d;                                                     \
        }                                                                     \
        var *= (1.0f / PDW);                                                  \
        float inv = 1.0f / sqrtf(var + 1e-5f);                                \
        _Pragma("unroll") for (int i = 0; i < PDW; ++i) {                     \
            float nv = (h[i] - mu) * inv * G[i] + Bv[i];                      \
            r[i] = fmaxf(nv, 0.f);                                            \
        }                                                                     \
    }

__device__ __forceinline__ float dpb_eval(float t, int hh,
    const float* __restrict__ w0, const float* __restrict__ b0,
    const float* __restrict__ g1, const float* __restrict__ gb1,
    const float* __restrict__ w1, const float* __restrict__ b1,
    const float* __restrict__ g2, const float* __restrict__ gb2,
    const float* __restrict__ w2, const float* __restrict__ b2,
    const float* __restrict__ g3, const float* __restrict__ gb3,
    const float* __restrict__ w3, const float* __restrict__ b3)
{
    float h[PDW], r[PDW];
    #pragma unroll
    for (int i = 0; i < PDW; ++i) h[i] = t * w0[i] + b0[i];
    LN_RELU(g1, gb1);
    #pragma unroll
    for (int j = 0; j < PDW; ++j) {
        float acc = b1[j];
        #pragma unroll
        for (int i = 0; i < PDW; ++i) acc += r[i] * w1[i * PDW + j];
        h[j] = acc;
    }
    LN_RELU(g2, gb2);
    #pragma unroll
    for (int j = 0; j < PDW; ++j) {
        float acc = b2[j];
        #pragma unroll
        for (int i = 0; i < PDW; ++i) acc += r[i] * w2[i * PDW + j];
        h[j] = acc;
    }
    LN_RELU(g3, gb3);
    float acc = b3[hh];
    #pragma unroll
    for (int i = 0; i < PDW; ++i) acc += r[i] * w3[i * NH + hh];
    return acc;
}

// One block per head: MLP (8 positions/thread, exactly the dpb values this
// thread's 16 a-entries need), build a, forward FFT, store V (layout matches
// conv's register order; 1/M folded in).
__global__ __launch_bounds__(256) void toeplitz_fused_kernel(
    const float* __restrict__ gamma,
    const float* __restrict__ w0, const float* __restrict__ b0,
    const float* __restrict__ g1, const float* __restrict__ gb1,
    const float* __restrict__ w1, const float* __restrict__ b1,
    const float* __restrict__ g2, const float* __restrict__ gb2,
    const float* __restrict__ w2, const float* __restrict__ b2,
    const float* __restrict__ g3, const float* __restrict__ gb3,
    const float* __restrict__ w3, const float* __restrict__ b3,
    float2* __restrict__ V)
{
    __shared__ float2 sh[MFFT];
    int hh = blockIdx.x;
    int tid = threadIdx.x;
    float lsg = -log1pf(__expf(-gamma[0]));  // log(sigmoid(gamma))
    float m[8];
    #pragma unroll
    for (int q = 0; q < 8; ++q)
        m[q] = dpb_eval((float)(tid + 256 * q), hh, w0, b0, g1, gb1, w1, b1,
                        g2, gb2, w2, b2, g3, gb3, w3, b3);
    float2 v[16];
    #pragma unroll
    for (int q = 0; q < 16; ++q) {
        int k = tid + 256 * q;
        float val;
        if (k == 0 || k == NPOS)  val = m[0];                        // zero_dpb (tid==0 only)
        else if (k < NPOS)        val = lsg * (float)k + m[q];
        else                      val = lsg * (float)(2 * NPOS - k) + m[q - 8];
        val = fminf(30.f, fmaxf(-60.f, val));
        v[q] = make_float2(__expf(val) * (1.0f / (float)MFFT), 0.f);
    }
    fft4096_fwd(v, sh, tid);
    #pragma unroll
    for (int k = 0; k < 16; ++k) V[hh * MFFT + 16 * tid + k] = v[k];
}

// One block per (b,h,e-pair); 256 threads x 16 float2. XCD-grouped: all 32
// pair-blocks of one (b,h) on the same XCD (head == XCD, so V[h] is
// single-XCD L2-resident too).
__global__ __launch_bounds__(256) void conv_kernel(
    const float* __restrict__ x, const float2* __restrict__ V,
    float* __restrict__ out)
{
    __shared__ float2 sh[MFFT];
    int wg = blockIdx.x;
    int xcd = wg & 7;
    int slot = wg >> 3;
    int pair = slot & 31;
    int bh = ((slot >> 5) << 3) | xcd;
    int h = bh & (NH - 1);
    int tid = threadIdx.x;

    const float* xp = x + (size_t)bh * NPOS * NE + pair * 2;
    float2 v[16];
    #pragma unroll
    for (int q = 0; q < 8; ++q)
        v[q] = *reinterpret_cast<const float2*>(xp + (size_t)(tid + 256 * q) * NE);
    #pragma unroll
    for (int q = 8; q < 16; ++q) v[q] = make_float2(0.f, 0.f);

    fft4096_fwd(v, sh, tid);

    const float4* V4 = reinterpret_cast<const float4*>(V + h * MFFT + 16 * tid);
    #pragma unroll
    for (int j = 0; j < 8; ++j) {
        float4 f = V4[j];
        v[2 * j]     = cmul(v[2 * j],     make_float2(f.x, f.y));
        v[2 * j + 1] = cmul(v[2 * j + 1], make_float2(f.z, f.w));
    }

    fft4096_inv(v, sh, tid);

    float* op = out + (size_t)bh * NPOS * NE + pair * 2;
    #pragma unroll
    for (int q = 0; q < 8; ++q)
        *reinterpret_cast<float2*>(op + (size_t)(tid + 256 * q) * NE) = v[q];
}

extern "C" void kernel_launch(void* const* d_in, const int* in_sizes, int n_in,
                              void* d_out, int out_size, void* d_ws, size_t ws_size,
                              hipStream_t stream) {
    const float* x     = (const float*)d_in[0];
    const float* gamma = (const float*)d_in[1];
    const float* w0    = (const float*)d_in[2];
    const float* b0    = (const float*)d_in[3];
    const float* g1    = (const float*)d_in[4];
    const float* gb1   = (const float*)d_in[5];
    const float* w1    = (const float*)d_in[6];
    const float* b1    = (const float*)d_in[7];
    const float* g2    = (const float*)d_in[8];
    const float* gb2   = (const float*)d_in[9];
    const float* w2    = (const float*)d_in[10];
    const float* b2    = (const float*)d_in[11];
    const float* g3    = (const float*)d_in[12];
    const float* gb3   = (const float*)d_in[13];
    const float* w3    = (const float*)d_in[14];
    const float* b3    = (const float*)d_in[15];
    float* out = (float*)d_out;

    float2* V = (float2*)d_ws;   // 8*4096 float2 = 256 KB

    toeplitz_fused_kernel<<<NH, 256, 0, stream>>>(gamma, w0, b0, g1, gb1, w1, b1,
                                                  g2, gb2, w2, b2, g3, gb3, w3, b3, V);
    conv_kernel<<<NB * NH * 32, 256, 0, stream>>>(x, V, out);
}

// Round 4
// 235.279 us; speedup vs baseline: 1.5129x; 1.5129x over previous
//
#include <hip/hip_runtime.h>
#include <math.h>

#define NPOS 2048   // n
#define MFFT 4096   // 2n
#define NH 8        // heads
#define PDW 16      // pos_dim
#define NE 64       // E
#define NB 16       // batch

__device__ __forceinline__ float2 cmul(float2 a, float2 b) {
    return make_float2(a.x * b.x - a.y * b.y, a.x * b.y + a.y * b.x);
}

#define C16_1 0.92387953251128674f
#define S16_1 0.38268343236508978f
#define C16_2 0.70710678118654757f

// 16-point DFT in registers, natural order in -> natural order out.
// SGN=-1: forward (e^{-2pi i nk/16}); SGN=+1: inverse (no 1/16 scaling).
template <int SGN>
__device__ __forceinline__ void dft16(float2 v[16]) {
    float2 y[16];
    // stage A: DFT4 over n2 (elements n1 + 4*n2), result k2 -> y[n1 + 4*k2]
    #pragma unroll
    for (int n1 = 0; n1 < 4; ++n1) {
        float2 a = v[n1], b = v[n1 + 4], c = v[n1 + 8], d = v[n1 + 12];
        float2 s02 = make_float2(a.x + c.x, a.y + c.y);
        float2 d02 = make_float2(a.x - c.x, a.y - c.y);
        float2 s13 = make_float2(b.x + d.x, b.y + d.y);
        float2 d13 = make_float2(b.x - d.x, b.y - d.y);
        float2 rot = (SGN < 0) ? make_float2(d13.y, -d13.x)   // -i * d13
                               : make_float2(-d13.y, d13.x);  // +i * d13
        y[n1]      = make_float2(s02.x + s13.x, s02.y + s13.y);
        y[n1 + 4]  = make_float2(d02.x + rot.x, d02.y + rot.y);
        y[n1 + 8]  = make_float2(s02.x - s13.x, s02.y - s13.y);
        y[n1 + 12] = make_float2(d02.x - rot.x, d02.y - rot.y);
    }
    // twiddles W16^{n1*k2} (conj for inverse)
    const float sg = (SGN < 0) ? -1.f : 1.f;
    const float2 W1 = make_float2(C16_1, sg * S16_1);
    const float2 W2 = make_float2(C16_2, sg * C16_2);
    const float2 W3 = make_float2(S16_1, sg * C16_1);
    const float2 W6 = make_float2(-C16_2, sg * C16_2);
    const float2 W9 = make_float2(-C16_1, -sg * S16_1);
    y[5]  = cmul(y[5],  W1);   // (n1=1,k2=1)
    y[9]  = cmul(y[9],  W2);   // (1,2)
    y[13] = cmul(y[13], W3);   // (1,3)
    y[6]  = cmul(y[6],  W2);   // (2,1)
    y[10] = (SGN < 0) ? make_float2(y[10].y, -y[10].x)        // (2,2): *W16^4 = -i
                      : make_float2(-y[10].y, y[10].x);
    y[14] = cmul(y[14], W6);   // (2,3)
    y[7]  = cmul(y[7],  W3);   // (3,1)
    y[11] = cmul(y[11], W6);   // (3,2)
    y[15] = cmul(y[15], W9);   // (3,3)
    // stage B: DFT4 over n1 (elements y[4*k2 + n1]), result k1 -> v[4*k1 + k2]
    #pragma unroll
    for (int k2 = 0; k2 < 4; ++k2) {
        float2 a = y[4 * k2], b = y[4 * k2 + 1], c = y[4 * k2 + 2], d = y[4 * k2 + 3];
        float2 s02 = make_float2(a.x + c.x, a.y + c.y);
        float2 d02 = make_float2(a.x - c.x, a.y - c.y);
        float2 s13 = make_float2(b.x + d.x, b.y + d.y);
        float2 d13 = make_float2(b.x - d.x, b.y - d.y);
        float2 rot = (SGN < 0) ? make_float2(d13.y, -d13.x)
                               : make_float2(-d13.y, d13.x);
        v[k2]      = make_float2(s02.x + s13.x, s02.y + s13.y);
        v[4 + k2]  = make_float2(d02.x + rot.x, d02.y + rot.y);
        v[8 + k2]  = make_float2(s02.x - s13.x, s02.y - s13.y);
        v[12 + k2] = make_float2(d02.x - rot.x, d02.y - rot.y);
    }
}

// Balanced-tree powers of w1: tw[k] = w1^k, depth 4 (vs 15-deep serial chain).
__device__ __forceinline__ void twtree(float2 w1, float2 tw[16]) {
    tw[1] = w1;
    tw[2]  = cmul(w1, w1);
    tw[3]  = cmul(tw[2], w1);
    tw[4]  = cmul(tw[2], tw[2]);
    tw[5]  = cmul(tw[2], tw[3]);
    tw[6]  = cmul(tw[3], tw[3]);
    tw[7]  = cmul(tw[3], tw[4]);
    tw[8]  = cmul(tw[4], tw[4]);
    tw[9]  = cmul(tw[4], tw[5]);
    tw[10] = cmul(tw[5], tw[5]);
    tw[11] = cmul(tw[5], tw[6]);
    tw[12] = cmul(tw[6], tw[6]);
    tw[13] = cmul(tw[6], tw[7]);
    tw[14] = cmul(tw[7], tw[7]);
    tw[15] = cmul(tw[7], tw[8]);
}

// 4096-pt FFT: 3 radix-16 register stages, 2 swizzled LDS transposes, 2 barriers.
// Input: v[q] = x[tid + 256 q] (natural). Output: v[k] = bin pi(16 tid + k)
// for a fixed digit-reversal pi (cancelled by fft4096_inv / matched by V).
// LDS swizzle: XOR of low digit with partner digit -> b64 bank floor.
__device__ __forceinline__ void fft4096_fwd(float2 v[16], float2* sh, int tid) {
    dft16<-1>(v);
    {
        float2 w1; __sincosf(-1.5339807878856412e-3f * (float)tid, &w1.y, &w1.x); // -2pi/4096 * tid
        float2 tw[16];
        twtree(w1, tw);
        int tA = tid ^ (tid >> 4);
        sh[tA] = v[0];
        #pragma unroll
        for (int k = 1; k < 16; ++k) sh[tA + 256 * k] = cmul(v[k], tw[k]);
    }
    __syncthreads();
    int t2 = tid & 15, bb = tid >> 4, baseB = bb * 256;
    #pragma unroll
    for (int k = 0; k < 16; ++k) v[k] = sh[baseB + 16 * k + (t2 ^ k)];
    dft16<-1>(v);
    {
        float2 w1; __sincosf(-2.4543692606170259e-2f * (float)t2, &w1.y, &w1.x); // -2pi/256 * t2
        float2 tw[16];
        twtree(w1, tw);
        sh[baseB + t2] = v[0];
        #pragma unroll
        for (int k = 1; k < 16; ++k) sh[baseB + 16 * k + (t2 ^ k)] = cmul(v[k], tw[k]);
    }
    __syncthreads();
    int tC = tid & 15;
    #pragma unroll
    for (int q = 0; q < 16; ++q) v[q] = sh[16 * tid + (q ^ tC)];
    dft16<-1>(v);
}

// Exact step-mirror of fft4096_fwd. Input: register layout produced by fwd.
// Output: v[q] = x[tid + 256 q] natural. No 1/M scaling (folded into V).
__device__ __forceinline__ void fft4096_inv(float2 v[16], float2* sh, int tid) {
    dft16<1>(v);
    int tC = tid & 15;
    #pragma unroll
    for (int q = 0; q < 16; ++q) sh[16 * tid + (q ^ tC)] = v[q];
    __syncthreads();
    int t2 = tid & 15, bb = tid >> 4, baseB = bb * 256;
    #pragma unroll
    for (int k = 0; k < 16; ++k) v[k] = sh[baseB + 16 * k + (t2 ^ k)];
    {
        float2 w1; __sincosf(2.4543692606170259e-2f * (float)t2, &w1.y, &w1.x);
        float2 tw[16];
        twtree(w1, tw);
        #pragma unroll
        for (int k = 1; k < 16; ++k) v[k] = cmul(v[k], tw[k]);
    }
    dft16<1>(v);
    #pragma unroll
    for (int q = 0; q < 16; ++q) sh[baseB + 16 * q + (t2 ^ q)] = v[q];
    __syncthreads();
    int tA = tid ^ (tid >> 4);
    #pragma unroll
    for (int k = 0; k < 16; ++k) v[k] = sh[tA + 256 * k];
    {
        float2 w1; __sincosf(1.5339807878856412e-3f * (float)tid, &w1.y, &w1.x);
        float2 tw[16];
        twtree(w1, tw);
        #pragma unroll
        for (int k = 1; k < 16; ++k) v[k] = cmul(v[k], tw[k]);
    }
    dft16<1>(v);
}

#define LN_RELU(G, Bv)                                                        \
    {                                                                         \
        float mu = 0.f;                                                       \
        _Pragma("unroll") for (int i = 0; i < PDW; ++i) mu += h[i];           \
        mu *= (1.0f / PDW);                                                   \
        float var = 0.f;                                                      \
        _Pragma("unroll") for (int i = 0; i < PDW; ++i) {                     \
            float d = h[i] - mu;                                              \
            var += d * d;                                                     \
        }                                                                     \
        var *= (1.0f / PDW);                                                  \
        float inv = 1.0f / sqrtf(var + 1e-5f);                                \
        _Pragma("unroll") for (int i = 0; i < PDW; ++i) {                     \
            float nv = (h[i] - mu) * inv * G[i] + Bv[i];                      \
            r[i] = fmaxf(nv, 0.f);                                            \
        }                                                                     \
    }

// One thread per (position, head): 16384 threads / 64 blocks.
// First 3 layers recomputed per head (free ILP); final layer is one column.
__global__ __launch_bounds__(256) void dpb_mlp_kernel(
    const float* __restrict__ w0, const float* __restrict__ b0,
    const float* __restrict__ g1, const float* __restrict__ gb1,
    const float* __restrict__ w1, const float* __restrict__ b1,
    const float* __restrict__ g2, const float* __restrict__ gb2,
    const float* __restrict__ w2, const float* __restrict__ b2,
    const float* __restrict__ g3, const float* __restrict__ gb3,
    const float* __restrict__ w3, const float* __restrict__ b3,
    float* __restrict__ dpbout)
{
    int idx = blockIdx.x * 256 + threadIdx.x;   // idx = p*8 + h
    int hh = idx & 7;
    float t = (float)(idx >> 3);
    float h[PDW], r[PDW];
    #pragma unroll
    for (int i = 0; i < PDW; ++i) h[i] = t * w0[i] + b0[i];
    LN_RELU(g1, gb1);
    #pragma unroll
    for (int j = 0; j < PDW; ++j) {
        float acc = b1[j];
        #pragma unroll
        for (int i = 0; i < PDW; ++i) acc += r[i] * w1[i * PDW + j];
        h[j] = acc;
    }
    LN_RELU(g2, gb2);
    #pragma unroll
    for (int j = 0; j < PDW; ++j) {
        float acc = b2[j];
        #pragma unroll
        for (int i = 0; i < PDW; ++i) acc += r[i] * w2[i * PDW + j];
        h[j] = acc;
    }
    LN_RELU(g3, gb3);
    float acc = b3[hh];
    #pragma unroll
    for (int i = 0; i < PDW; ++i) acc += r[i] * w3[i * NH + hh];
    dpbout[idx] = acc;
}

// One block per head: build a[h][4096] from dpbout, fwd FFT, store V
// (register-order layout 16*tid+k matching conv; 1/M folded in).
__global__ __launch_bounds__(256) void toeplitz_fft_kernel(
    const float* __restrict__ gamma, const float* __restrict__ dpbout,
    float2* __restrict__ V)
{
    __shared__ float2 sh[MFFT];
    int hh = blockIdx.x;
    int tid = threadIdx.x;
    float lsg = -log1pf(__expf(-gamma[0]));  // log(sigmoid(gamma))
    float2 v[16];
    #pragma unroll
    for (int q = 0; q < 16; ++q) {
        int k = tid + 256 * q;
        float val;
        if (k == 0 || k == NPOS)  val = dpbout[hh];                      // zero_dpb
        else if (k < NPOS)        val = lsg * (float)k + dpbout[k * NH + hh];
        else                      val = lsg * (float)(2 * NPOS - k) + dpbout[(k - NPOS) * NH + hh];
        val = fminf(30.f, fmaxf(-60.f, val));
        v[q] = make_float2(__expf(val) * (1.0f / (float)MFFT), 0.f);
    }
    fft4096_fwd(v, sh, tid);
    #pragma unroll
    for (int k = 0; k < 16; ++k) V[hh * MFFT + 16 * tid + k] = v[k];
}

// One block per (b,h,e-pair); 256 threads x 16 float2. XCD-grouped: all 32
// pair-blocks of one (b,h) on the same XCD (head == XCD, so V[h] is
// single-XCD L2-resident too).
__global__ __launch_bounds__(256) void conv_kernel(
    const float* __restrict__ x, const float2* __restrict__ V,
    float* __restrict__ out)
{
    __shared__ float2 sh[MFFT];
    int wg = blockIdx.x;
    int xcd = wg & 7;
    int slot = wg >> 3;
    int pair = slot & 31;
    int bh = ((slot >> 5) << 3) | xcd;
    int h = bh & (NH - 1);
    int tid = threadIdx.x;

    const float* xp = x + (size_t)bh * NPOS * NE + pair * 2;
    float2 v[16];
    #pragma unroll
    for (int q = 0; q < 8; ++q)
        v[q] = *reinterpret_cast<const float2*>(xp + (size_t)(tid + 256 * q) * NE);
    #pragma unroll
    for (int q = 8; q < 16; ++q) v[q] = make_float2(0.f, 0.f);

    fft4096_fwd(v, sh, tid);

    const float4* V4 = reinterpret_cast<const float4*>(V + h * MFFT + 16 * tid);
    #pragma unroll
    for (int j = 0; j < 8; ++j) {
        float4 f = V4[j];
        v[2 * j]     = cmul(v[2 * j],     make_float2(f.x, f.y));
        v[2 * j + 1] = cmul(v[2 * j + 1], make_float2(f.z, f.w));
    }

    fft4096_inv(v, sh, tid);

    float* op = out + (size_t)bh * NPOS * NE + pair * 2;
    #pragma unroll
    for (int q = 0; q < 8; ++q)
        *reinterpret_cast<float2*>(op + (size_t)(tid + 256 * q) * NE) = v[q];
}

extern "C" void kernel_launch(void* const* d_in, const int* in_sizes, int n_in,
                              void* d_out, int out_size, void* d_ws, size_t ws_size,
                              hipStream_t stream) {
    const float* x     = (const float*)d_in[0];
    const float* gamma = (const float*)d_in[1];
    const float* w0    = (const float*)d_in[2];
    const float* b0    = (const float*)d_in[3];
    const float* g1    = (const float*)d_in[4];
    const float* gb1   = (const float*)d_in[5];
    const float* w1    = (const float*)d_in[6];
    const float* b1    = (const float*)d_in[7];
    const float* g2    = (const float*)d_in[8];
    const float* gb2   = (const float*)d_in[9];
    const float* w2    = (const float*)d_in[10];
    const float* b2    = (const float*)d_in[11];
    const float* g3    = (const float*)d_in[12];
    const float* gb3   = (const float*)d_in[13];
    const float* w3    = (const float*)d_in[14];
    const float* b3    = (const float*)d_in[15];
    float* out = (float*)d_out;

    float*  dpbout = (float*)d_ws;                    // 2048*8 fp32 = 64 KB
    float2* V      = (float2*)((char*)d_ws + 65536);  // 8*4096 float2 = 256 KB

    dpb_mlp_kernel<<<NPOS * NH / 256, 256, 0, stream>>>(w0, b0, g1, gb1, w1, b1,
                                                        g2, gb2, w2, b2, g3, gb3,
                                                        w3, b3, dpbout);
    toeplitz_fft_kernel<<<NH, 256, 0, stream>>>(gamma, dpbout, V);
    conv_kernel<<<NB * NH * 32, 256, 0, stream>>>(x, V, out);
}

// Round 5
// 230.493 us; speedup vs baseline: 1.5443x; 1.0208x over previous
//
#include <hip/hip_runtime.h>
#include <math.h>

#define NPOS 2048   // n
#define MFFT 4096   // 2n
#define NH 8        // heads
#define PDW 16      // pos_dim
#define NE 64       // E
#define NB 16       // batch

__device__ __forceinline__ float2 cmul(float2 a, float2 b) {
    return make_float2(a.x * b.x - a.y * b.y, a.x * b.y + a.y * b.x);
}
__device__ __forceinline__ float2 f2add(float2 a, float2 b) {
    return make_float2(a.x + b.x, a.y + b.y);
}
__device__ __forceinline__ float2 f2sub(float2 a, float2 b) {
    return make_float2(a.x - b.x, a.y - b.y);
}

// LDS swizzle: base-8 digits d0^=d1, d1^=d2. Bijective; makes every stage's
// wave access exactly 2-way bank aliasing (free). Applied to ALL LDS ops.
__device__ __forceinline__ int swz(int a) {
    return a ^ ((a >> 3) & 7) ^ (((a >> 6) & 7) << 3);
}

// 8-point DFT, natural in -> natural out. SGN=-1 fwd, +1 inv (no 1/8 scale).
// MODE: 0 full; 1 = inputs v[4..7] are zero (skip their adds); 2 = only
// outputs v[0..3] needed.
template <int SGN, int MODE>
__device__ __forceinline__ void dft8(float2 v[8]) {
    const float c = 0.70710678118654757f;
    float2 E0, E1, E2, E3, O0, O1, O2, O3;
    if (MODE == 1) {
        float2 a = v[0], b = v[2];
        E0 = f2add(a, b); E2 = f2sub(a, b);
        E1 = (SGN < 0) ? make_float2(a.x + b.y, a.y - b.x) : make_float2(a.x - b.y, a.y + b.x);
        E3 = (SGN < 0) ? make_float2(a.x - b.y, a.y + b.x) : make_float2(a.x + b.y, a.y - b.x);
        a = v[1]; b = v[3];
        O0 = f2add(a, b); O2 = f2sub(a, b);
        O1 = (SGN < 0) ? make_float2(a.x + b.y, a.y - b.x) : make_float2(a.x - b.y, a.y + b.x);
        O3 = (SGN < 0) ? make_float2(a.x - b.y, a.y + b.x) : make_float2(a.x + b.y, a.y - b.x);
    } else {
        float2 t0 = f2add(v[0], v[4]), t1 = f2sub(v[0], v[4]);
        float2 t2 = f2add(v[2], v[6]), t3 = f2sub(v[2], v[6]);
        E0 = f2add(t0, t2); E2 = f2sub(t0, t2);
        E1 = (SGN < 0) ? make_float2(t1.x + t3.y, t1.y - t3.x) : make_float2(t1.x - t3.y, t1.y + t3.x);
        E3 = (SGN < 0) ? make_float2(t1.x - t3.y, t1.y + t3.x) : make_float2(t1.x + t3.y, t1.y - t3.x);
        t0 = f2add(v[1], v[5]); t1 = f2sub(v[1], v[5]);
        t2 = f2add(v[3], v[7]); t3 = f2sub(v[3], v[7]);
        O0 = f2add(t0, t2); O2 = f2sub(t0, t2);
        O1 = (SGN < 0) ? make_float2(t1.x + t3.y, t1.y - t3.x) : make_float2(t1.x - t3.y, t1.y + t3.x);
        O3 = (SGN < 0) ? make_float2(t1.x - t3.y, t1.y + t3.x) : make_float2(t1.x + t3.y, t1.y - t3.x);
    }
    // W8^k * O[k]
    float2 w1O, w2O, w3O;
    if (SGN < 0) {
        w1O = make_float2(c * (O1.x + O1.y), c * (O1.y - O1.x));
        w2O = make_float2(O2.y, -O2.x);
        w3O = make_float2(c * (O3.y - O3.x), -c * (O3.x + O3.y));
    } else {
        w1O = make_float2(c * (O1.x - O1.y), c * (O1.y + O1.x));
        w2O = make_float2(-O2.y, O2.x);
        w3O = make_float2(-c * (O3.x + O3.y), c * (O3.x - O3.y));
    }
    v[0] = f2add(E0, O0); v[1] = f2add(E1, w1O);
    v[2] = f2add(E2, w2O); v[3] = f2add(E3, w3O);
    if (MODE != 2) {
        v[4] = f2sub(E0, O0); v[5] = f2sub(E1, w1O);
        v[6] = f2sub(E2, w2O); v[7] = f2sub(E3, w3O);
    }
}

// u[j] *= e^{i ang j}, j=1..7 (balanced tree, depth 3)
__device__ __forceinline__ void twiddle8(float2 u[8], float ang) {
    float2 w1; __sincosf(ang, &w1.y, &w1.x);
    float2 w2 = cmul(w1, w1), w3 = cmul(w1, w2), w4 = cmul(w2, w2);
    float2 w5 = cmul(w2, w3), w6 = cmul(w3, w3), w7 = cmul(w3, w4);
    u[1] = cmul(u[1], w1); u[2] = cmul(u[2], w2); u[3] = cmul(u[3], w3);
    u[4] = cmul(u[4], w4); u[5] = cmul(u[5], w5); u[6] = cmul(u[6], w6);
    u[7] = cmul(u[7], w7);
}

#define A4096 1.5339807878856412e-3f   // 2pi/4096
#define A512  1.2271846303085130e-2f   // 2pi/512
#define A64   9.8174770424681035e-2f   // 2pi/64

// Forward 4096-pt FFT, radix-8 DIF, 512 threads, in-place swizzled LDS.
// In: v[r] = x[m + 512 r] natural. Out: v[j] = bin pi(8 m + j), fixed
// digit-reversal pi (matched by V / inverted by the inverse).
// MODE1: 1 if v[4..7] are zero on entry (conv's zero padding), else 0.
template <int MODE1>
__device__ __forceinline__ void fftR8_fwd(float2 v[8], float2* sh, int m) {
    dft8<-1, MODE1>(v);
    twiddle8(v, -A4096 * (float)m);
    #pragma unroll
    for (int j = 0; j < 8; ++j) sh[swz(m + 512 * j)] = v[j];
    __syncthreads();
    int t2 = m & 63, b2 = (m >> 6) << 9;
    #pragma unroll
    for (int r = 0; r < 8; ++r) v[r] = sh[swz(b2 + t2 + 64 * r)];
    dft8<-1, 0>(v);
    twiddle8(v, -A512 * (float)t2);
    #pragma unroll
    for (int j = 0; j < 8; ++j) sh[swz(b2 + t2 + 64 * j)] = v[j];
    __syncthreads();
    int t3 = m & 7, b3 = (m >> 3) << 6;
    #pragma unroll
    for (int r = 0; r < 8; ++r) v[r] = sh[swz(b3 + t3 + 8 * r)];
    dft8<-1, 0>(v);
    twiddle8(v, -A64 * (float)t3);
    #pragma unroll
    for (int j = 0; j < 8; ++j) sh[swz(b3 + t3 + 8 * j)] = v[j];
    __syncthreads();
    int b4 = m << 3;
    #pragma unroll
    for (int r = 0; r < 8; ++r) v[r] = sh[swz(b4 + r)];
    dft8<-1, 0>(v);
}

#define LN_RELU(G, Bv)                                                        \
    {                                                                         \
        float mu = 0.f;                                                       \
        _Pragma("unroll") for (int i = 0; i < PDW; ++i) mu += h[i];           \
        mu *= (1.0f / PDW);                                                   \
        float var = 0.f;                                                      \
        _Pragma("unroll") for (int i = 0; i < PDW; ++i) {                     \
            float d = h[i] - mu;                                              \
            var += d * d;                                                     \
        }                                                                     \
        var *= (1.0f / PDW);                                                  \
        float inv = 1.0f / sqrtf(var + 1e-5f);                                \
        _Pragma("unroll") for (int i = 0; i < PDW; ++i) {                     \
            float nv = (h[i] - mu) * inv * G[i] + Bv[i];                      \
            r[i] = fmaxf(nv, 0.f);                                            \
        }                                                                     \
    }

// One thread per (position, head): 16384 threads / 64 blocks.
__global__ __launch_bounds__(256) void dpb_mlp_kernel(
    const float* __restrict__ w0, const float* __restrict__ b0,
    const float* __restrict__ g1, const float* __restrict__ gb1,
    const float* __restrict__ w1, const float* __restrict__ b1,
    const float* __restrict__ g2, const float* __restrict__ gb2,
    const float* __restrict__ w2, const float* __restrict__ b2,
    const float* __restrict__ g3, const float* __restrict__ gb3,
    const float* __restrict__ w3, const float* __restrict__ b3,
    float* __restrict__ dpbout)
{
    int idx = blockIdx.x * 256 + threadIdx.x;   // idx = p*8 + h
    int hh = idx & 7;
    float t = (float)(idx >> 3);
    float h[PDW], r[PDW];
    #pragma unroll
    for (int i = 0; i < PDW; ++i) h[i] = t * w0[i] + b0[i];
    LN_RELU(g1, gb1);
    #pragma unroll
    for (int j = 0; j < PDW; ++j) {
        float acc = b1[j];
        #pragma unroll
        for (int i = 0; i < PDW; ++i) acc += r[i] * w1[i * PDW + j];
        h[j] = acc;
    }
    LN_RELU(g2, gb2);
    #pragma unroll
    for (int j = 0; j < PDW; ++j) {
        float acc = b2[j];
        #pragma unroll
        for (int i = 0; i < PDW; ++i) acc += r[i] * w2[i * PDW + j];
        h[j] = acc;
    }
    LN_RELU(g3, gb3);
    float acc = b3[hh];
    #pragma unroll
    for (int i = 0; i < PDW; ++i) acc += r[i] * w3[i * NH + hh];
    dpbout[idx] = acc;
}

// One block per head, 512 threads: build a[h], fwd FFT, store V in the
// register-order layout V[h][8m + j] (1/M folded in).
__global__ __launch_bounds__(512) void toeplitz_fft_kernel(
    const float* __restrict__ gamma, const float* __restrict__ dpbout,
    float2* __restrict__ V)
{
    __shared__ float2 sh[MFFT];
    int hh = blockIdx.x;
    int m = threadIdx.x;
    float lsg = -log1pf(__expf(-gamma[0]));  // log(sigmoid(gamma))
    float2 v[8];
    #pragma unroll
    for (int r = 0; r < 8; ++r) {
        int k = m + 512 * r;
        float val;
        if (k == 0 || k == NPOS)  val = dpbout[hh];                       // zero_dpb
        else if (k < NPOS)        val = lsg * (float)k + dpbout[k * NH + hh];
        else                      val = lsg * (float)(2 * NPOS - k) + dpbout[(k - NPOS) * NH + hh];
        val = fminf(30.f, fmaxf(-60.f, val));
        v[r] = make_float2(__expf(val) * (1.0f / (float)MFFT), 0.f);
    }
    fftR8_fwd<0>(v, sh, m);
    #pragma unroll
    for (int j = 0; j < 8; ++j) V[hh * MFFT + 8 * m + j] = v[j];
}

// One block per (b,h,e-pair), 512 threads x 8 float2. XCD-grouped as before.
__global__ __launch_bounds__(512) void conv_kernel(
    const float* __restrict__ x, const float2* __restrict__ V,
    float* __restrict__ out)
{
    __shared__ float2 sh[MFFT];
    int wg = blockIdx.x;
    int xcd = wg & 7;
    int slot = wg >> 3;
    int pair = slot & 31;
    int bh = ((slot >> 5) << 3) | xcd;
    int h = bh & (NH - 1);
    int m = threadIdx.x;

    const float* xp = x + (size_t)bh * NPOS * NE + pair * 2;
    float2 v[8];
    #pragma unroll
    for (int r = 0; r < 4; ++r)
        v[r] = *reinterpret_cast<const float2*>(xp + (size_t)(m + 512 * r) * NE);
    // v[4..7] are the zero padding: never read (MODE1=1), set for safety
    #pragma unroll
    for (int r = 4; r < 8; ++r) v[r] = make_float2(0.f, 0.f);

    fftR8_fwd<1>(v, sh, m);

    int b4 = m << 3;
    const float4* V4 = reinterpret_cast<const float4*>(V + h * MFFT + b4);
    #pragma unroll
    for (int j2 = 0; j2 < 4; ++j2) {
        float4 f = V4[j2];
        v[2 * j2]     = cmul(v[2 * j2],     make_float2(f.x, f.y));
        v[2 * j2 + 1] = cmul(v[2 * j2 + 1], make_float2(f.z, f.w));
    }

    // ---- inverse: exact stage-mirror, conjugate twiddles ----
    dft8<1, 0>(v);
    #pragma unroll
    for (int r = 0; r < 8; ++r) sh[swz(b4 + r)] = v[r];
    __syncthreads();
    int t3 = m & 7, b3 = (m >> 3) << 6;
    #pragma unroll
    for (int j = 0; j < 8; ++j) v[j] = sh[swz(b3 + t3 + 8 * j)];
    twiddle8(v, A64 * (float)t3);
    dft8<1, 0>(v);
    #pragma unroll
    for (int r = 0; r < 8; ++r) sh[swz(b3 + t3 + 8 * r)] = v[r];
    __syncthreads();
    int t2 = m & 63, b2 = (m >> 6) << 9;
    #pragma unroll
    for (int j = 0; j < 8; ++j) v[j] = sh[swz(b2 + t2 + 64 * j)];
    twiddle8(v, A512 * (float)t2);
    dft8<1, 0>(v);
    #pragma unroll
    for (int r = 0; r < 8; ++r) sh[swz(b2 + t2 + 64 * r)] = v[r];
    __syncthreads();
    #pragma unroll
    for (int j = 0; j < 8; ++j) v[j] = sh[swz(m + 512 * j)];
    twiddle8(v, A4096 * (float)m);
    dft8<1, 2>(v);   // only v[0..3] needed (rows 0..2047)

    float* op = out + (size_t)bh * NPOS * NE + pair * 2;
    #pragma unroll
    for (int r = 0; r < 4; ++r)
        *reinterpret_cast<float2*>(op + (size_t)(m + 512 * r) * NE) = v[r];
}

extern "C" void kernel_launch(void* const* d_in, const int* in_sizes, int n_in,
                              void* d_out, int out_size, void* d_ws, size_t ws_size,
                              hipStream_t stream) {
    const float* x     = (const float*)d_in[0];
    const float* gamma = (const float*)d_in[1];
    const float* w0    = (const float*)d_in[2];
    const float* b0    = (const float*)d_in[3];
    const float* g1    = (const float*)d_in[4];
    const float* gb1   = (const float*)d_in[5];
    const float* w1    = (const float*)d_in[6];
    const float* b1    = (const float*)d_in[7];
    const float* g2    = (const float*)d_in[8];
    const float* gb2   = (const float*)d_in[9];
    const float* w2    = (const float*)d_in[10];
    const float* b2    = (const float*)d_in[11];
    const float* g3    = (const float*)d_in[12];
    const float* gb3   = (const float*)d_in[13];
    const float* w3    = (const float*)d_in[14];
    const float* b3    = (const float*)d_in[15];
    float* out = (float*)d_out;

    float*  dpbout = (float*)d_ws;                    // 2048*8 fp32 = 64 KB
    float2* V      = (float2*)((char*)d_ws + 65536);  // 8*4096 float2 = 256 KB

    dpb_mlp_kernel<<<NPOS * NH / 256, 256, 0, stream>>>(w0, b0, g1, gb1, w1, b1,
                                                        g2, gb2, w2, b2, g3, gb3,
                                                        w3, b3, dpbout);
    toeplitz_fft_kernel<<<NH, 512, 0, stream>>>(gamma, dpbout, V);
    conv_kernel<<<NB * NH * 32, 512, 0, stream>>>(x, V, out);
}

// Round 6
// 224.729 us; speedup vs baseline: 1.5840x; 1.0256x over previous
//
#include <hip/hip_runtime.h>
#include <math.h>

#define NPOS 2048   // n
#define MFFT 4096   // 2n
#define NH 8        // heads
#define PDW 16      // pos_dim
#define NE 64       // E
#define NB 16       // batch

// native 2-wide float vector -> compiler emits v_pk_*_f32 packed math
typedef float v2f __attribute__((ext_vector_type(2)));

// rot<SGN>(z): SGN=-1 -> -i*z = (z.y, -z.x); SGN=+1 -> +i*z = (-z.y, z.x)
template <int SGN>
__device__ __forceinline__ v2f rot(v2f z) {
    return (SGN < 0) ? (v2f){z.y, -z.x} : (v2f){-z.y, z.x};
}

__device__ __forceinline__ v2f cmul(v2f a, v2f b) {
    // (ax*bx - ay*by, ax*by + ay*bx) = a.xx*b + a.yy*(-b.y, b.x)
    return a.xx * b + a.yy * (v2f){-b.y, b.x};
}

// LDS swizzle: base-8 digits d0^=d1, d1^=d2. Bijective; every stage's wave
// access is exactly 2-way bank aliasing (free). Applied to ALL LDS ops.
__device__ __forceinline__ int swz(int a) {
    return a ^ ((a >> 3) & 7) ^ (((a >> 6) & 7) << 3);
}

// 8-point DFT, natural in -> natural out. SGN=-1 fwd, +1 inv (no 1/8 scale).
// MODE: 0 full; 1 = inputs v[4..7] are zero; 2 = only outputs v[0..3] needed.
template <int SGN, int MODE>
__device__ __forceinline__ void dft8(v2f v[8]) {
    const float c = 0.70710678118654757f;
    v2f E0, E1, E2, E3, O0, O1, O2, O3;
    if (MODE == 1) {
        v2f a = v[0], b = v[2];
        E0 = a + b; E2 = a - b; E1 = a + rot<SGN>(b); E3 = a - rot<SGN>(b);
        a = v[1]; b = v[3];
        O0 = a + b; O2 = a - b; O1 = a + rot<SGN>(b); O3 = a - rot<SGN>(b);
    } else {
        v2f t0 = v[0] + v[4], t1 = v[0] - v[4];
        v2f t2 = v[2] + v[6], t3 = v[2] - v[6];
        E0 = t0 + t2; E2 = t0 - t2;
        E1 = t1 + rot<SGN>(t3); E3 = t1 - rot<SGN>(t3);
        t0 = v[1] + v[5]; t1 = v[1] - v[5];
        t2 = v[3] + v[7]; t3 = v[3] - v[7];
        O0 = t0 + t2; O2 = t0 - t2;
        O1 = t1 + rot<SGN>(t3); O3 = t1 - rot<SGN>(t3);
    }
    // W8^k * O[k]: W8^1*z = c*(z + rot(z)), W8^2*z = rot(z), W8^3*z = c*(rot(z) - z)
    v2f w1O = c * (O1 + rot<SGN>(O1));
    v2f w2O = rot<SGN>(O2);
    v2f w3O = c * (rot<SGN>(O3) - O3);
    v[0] = E0 + O0; v[1] = E1 + w1O; v[2] = E2 + w2O; v[3] = E3 + w3O;
    if (MODE != 2) {
        v[4] = E0 - O0; v[5] = E1 - w1O; v[6] = E2 - w2O; v[7] = E3 - w3O;
    }
}

// u[j] *= e^{i ang j}, j=1..7 (balanced tree, depth 3)
__device__ __forceinline__ void twiddle8(v2f u[8], float ang) {
    float sn, cs;
    __sincosf(ang, &sn, &cs);
    v2f w1 = (v2f){cs, sn};
    v2f w2 = cmul(w1, w1), w3 = cmul(w1, w2), w4 = cmul(w2, w2);
    v2f w5 = cmul(w2, w3), w6 = cmul(w3, w3), w7 = cmul(w3, w4);
    u[1] = cmul(u[1], w1); u[2] = cmul(u[2], w2); u[3] = cmul(u[3], w3);
    u[4] = cmul(u[4], w4); u[5] = cmul(u[5], w5); u[6] = cmul(u[6], w6);
    u[7] = cmul(u[7], w7);
}

#define A4096 1.5339807878856412e-3f   // 2pi/4096
#define A512  1.2271846303085130e-2f   // 2pi/512
#define A64   9.8174770424681035e-2f   // 2pi/64

// Forward 4096-pt FFT, radix-8 DIF, 512 threads, in-place swizzled LDS.
// In: v[r] = x[m + 512 r] natural. Out: v[j] = bin pi(8 m + j), fixed
// digit-reversal pi (matched by V / inverted by the inverse).
// MODE1: 1 if v[4..7] are zero on entry (conv's zero padding), else 0.
template <int MODE1>
__device__ __forceinline__ void fftR8_fwd(v2f v[8], v2f* sh, int m) {
    dft8<-1, MODE1>(v);
    twiddle8(v, -A4096 * (float)m);
    #pragma unroll
    for (int j = 0; j < 8; ++j) sh[swz(m + 512 * j)] = v[j];
    __syncthreads();
    int t2 = m & 63, b2 = (m >> 6) << 9;
    #pragma unroll
    for (int r = 0; r < 8; ++r) v[r] = sh[swz(b2 + t2 + 64 * r)];
    dft8<-1, 0>(v);
    twiddle8(v, -A512 * (float)t2);
    #pragma unroll
    for (int j = 0; j < 8; ++j) sh[swz(b2 + t2 + 64 * j)] = v[j];
    __syncthreads();
    int t3 = m & 7, b3 = (m >> 3) << 6;
    #pragma unroll
    for (int r = 0; r < 8; ++r) v[r] = sh[swz(b3 + t3 + 8 * r)];
    dft8<-1, 0>(v);
    twiddle8(v, -A64 * (float)t3);
    #pragma unroll
    for (int j = 0; j < 8; ++j) sh[swz(b3 + t3 + 8 * j)] = v[j];
    __syncthreads();
    int b4 = m << 3;
    #pragma unroll
    for (int r = 0; r < 8; ++r) v[r] = sh[swz(b4 + r)];
    dft8<-1, 0>(v);
}

#define LN_RELU(G, Bv)                                                        \
    {                                                                         \
        float mu = 0.f;                                                       \
        _Pragma("unroll") for (int i = 0; i < PDW; ++i) mu += h[i];           \
        mu *= (1.0f / PDW);                                                   \
        float var = 0.f;                                                      \
        _Pragma("unroll") for (int i = 0; i < PDW; ++i) {                     \
            float d = h[i] - mu;                                              \
            var += d * d;                                                     \
        }                                                                     \
        var *= (1.0f / PDW);                                                  \
        float inv = 1.0f / sqrtf(var + 1e-5f);                                \
        _Pragma("unroll") for (int i = 0; i < PDW; ++i) {                     \
            float nv = (h[i] - mu) * inv * G[i] + Bv[i];                      \
            r[i] = fmaxf(nv, 0.f);                                            \
        }                                                                     \
    }

// One thread per (position, head): 16384 threads / 64 blocks.
__global__ __launch_bounds__(256) void dpb_mlp_kernel(
    const float* __restrict__ w0, const float* __restrict__ b0,
    const float* __restrict__ g1, const float* __restrict__ gb1,
    const float* __restrict__ w1, const float* __restrict__ b1,
    const float* __restrict__ g2, const float* __restrict__ gb2,
    const float* __restrict__ w2, const float* __restrict__ b2,
    const float* __restrict__ g3, const float* __restrict__ gb3,
    const float* __restrict__ w3, const float* __restrict__ b3,
    float* __restrict__ dpbout)
{
    int idx = blockIdx.x * 256 + threadIdx.x;   // idx = p*8 + h
    int hh = idx & 7;
    float t = (float)(idx >> 3);
    float h[PDW], r[PDW];
    #pragma unroll
    for (int i = 0; i < PDW; ++i) h[i] = t * w0[i] + b0[i];
    LN_RELU(g1, gb1);
    #pragma unroll
    for (int j = 0; j < PDW; ++j) {
        float acc = b1[j];
        #pragma unroll
        for (int i = 0; i < PDW; ++i) acc += r[i] * w1[i * PDW + j];
        h[j] = acc;
    }
    LN_RELU(g2, gb2);
    #pragma unroll
    for (int j = 0; j < PDW; ++j) {
        float acc = b2[j];
        #pragma unroll
        for (int i = 0; i < PDW; ++i) acc += r[i] * w2[i * PDW + j];
        h[j] = acc;
    }
    LN_RELU(g3, gb3);
    float acc = b3[hh];
    #pragma unroll
    for (int i = 0; i < PDW; ++i) acc += r[i] * w3[i * NH + hh];
    dpbout[idx] = acc;
}

// One block per head, 512 threads: build a[h], fwd FFT, store V in the
// register-order layout V[h][8m + j] (1/M folded in).
__global__ __launch_bounds__(512) void toeplitz_fft_kernel(
    const float* __restrict__ gamma, const float* __restrict__ dpbout,
    v2f* __restrict__ V)
{
    __shared__ v2f sh[MFFT];
    int hh = blockIdx.x;
    int m = threadIdx.x;
    float lsg = -log1pf(__expf(-gamma[0]));  // log(sigmoid(gamma))
    v2f v[8];
    #pragma unroll
    for (int r = 0; r < 8; ++r) {
        int k = m + 512 * r;
        float val;
        if (k == 0 || k == NPOS)  val = dpbout[hh];                       // zero_dpb
        else if (k < NPOS)        val = lsg * (float)k + dpbout[k * NH + hh];
        else                      val = lsg * (float)(2 * NPOS - k) + dpbout[(k - NPOS) * NH + hh];
        val = fminf(30.f, fmaxf(-60.f, val));
        v[r] = (v2f){__expf(val) * (1.0f / (float)MFFT), 0.f};
    }
    fftR8_fwd<0>(v, sh, m);
    #pragma unroll
    for (int j = 0; j < 8; ++j) V[hh * MFFT + 8 * m + j] = v[j];
}

// One block per (b,h,e-pair), 512 threads x 8 v2f. XCD-grouped: all 32
// pair-blocks of one (b,h) on the same XCD (head == XCD, V[h] L2-resident).
__global__ __launch_bounds__(512) void conv_kernel(
    const float* __restrict__ x, const v2f* __restrict__ V,
    float* __restrict__ out)
{
    __shared__ v2f sh[MFFT];
    int wg = blockIdx.x;
    int xcd = wg & 7;
    int slot = wg >> 3;
    int pair = slot & 31;
    int bh = ((slot >> 5) << 3) | xcd;
    int h = bh & (NH - 1);
    int m = threadIdx.x;

    const float* xp = x + (size_t)bh * NPOS * NE + pair * 2;
    v2f v[8];
    #pragma unroll
    for (int r = 0; r < 4; ++r)
        v[r] = *reinterpret_cast<const v2f*>(xp + (size_t)(m + 512 * r) * NE);
    #pragma unroll
    for (int r = 4; r < 8; ++r) v[r] = (v2f){0.f, 0.f};

    fftR8_fwd<1>(v, sh, m);

    int b4 = m << 3;
    const v2f* Vh = V + h * MFFT + b4;
    #pragma unroll
    for (int j = 0; j < 8; ++j) v[j] = cmul(v[j], Vh[j]);

    // ---- inverse: exact stage-mirror, conjugate twiddles ----
    dft8<1, 0>(v);
    #pragma unroll
    for (int r = 0; r < 8; ++r) sh[swz(b4 + r)] = v[r];
    __syncthreads();
    int t3 = m & 7, b3 = (m >> 3) << 6;
    #pragma unroll
    for (int j = 0; j < 8; ++j) v[j] = sh[swz(b3 + t3 + 8 * j)];
    twiddle8(v, A64 * (float)t3);
    dft8<1, 0>(v);
    #pragma unroll
    for (int r = 0; r < 8; ++r) sh[swz(b3 + t3 + 8 * r)] = v[r];
    __syncthreads();
    int t2 = m & 63, b2 = (m >> 6) << 9;
    #pragma unroll
    for (int j = 0; j < 8; ++j) v[j] = sh[swz(b2 + t2 + 64 * j)];
    twiddle8(v, A512 * (float)t2);
    dft8<1, 0>(v);
    #pragma unroll
    for (int r = 0; r < 8; ++r) sh[swz(b2 + t2 + 64 * r)] = v[r];
    __syncthreads();
    #pragma unroll
    for (int j = 0; j < 8; ++j) v[j] = sh[swz(m + 512 * j)];
    twiddle8(v, A4096 * (float)m);
    dft8<1, 2>(v);   // only v[0..3] needed (rows 0..2047)

    float* op = out + (size_t)bh * NPOS * NE + pair * 2;
    #pragma unroll
    for (int r = 0; r < 4; ++r)
        *reinterpret_cast<v2f*>(op + (size_t)(m + 512 * r) * NE) = v[r];
}

extern "C" void kernel_launch(void* const* d_in, const int* in_sizes, int n_in,
                              void* d_out, int out_size, void* d_ws, size_t ws_size,
                              hipStream_t stream) {
    const float* x     = (const float*)d_in[0];
    const float* gamma = (const float*)d_in[1];
    const float* w0    = (const float*)d_in[2];
    const float* b0    = (const float*)d_in[3];
    const float* g1    = (const float*)d_in[4];
    const float* gb1   = (const float*)d_in[5];
    const float* w1    = (const float*)d_in[6];
    const float* b1    = (const float*)d_in[7];
    const float* g2    = (const float*)d_in[8];
    const float* gb2   = (const float*)d_in[9];
    const float* w2    = (const float*)d_in[10];
    const float* b2    = (const float*)d_in[11];
    const float* g3    = (const float*)d_in[12];
    const float* gb3   = (const float*)d_in[13];
    const float* w3    = (const float*)d_in[14];
    const float* b3    = (const float*)d_in[15];
    float* out = (float*)d_out;

    float* dpbout = (float*)d_ws;                  // 2048*8 fp32 = 64 KB
    v2f*   V      = (v2f*)((char*)d_ws + 65536);   // 8*4096 v2f = 256 KB

    dpb_mlp_kernel<<<NPOS * NH / 256, 256, 0, stream>>>(w0, b0, g1, gb1, w1, b1,
                                                        g2, gb2, w2, b2, g3, gb3,
                                                        w3, b3, dpbout);
    toeplitz_fft_kernel<<<NH, 512, 0, stream>>>(gamma, dpbout, V);
    conv_kernel<<<NB * NH * 32, 512, 0, stream>>>(x, V, out);
}

// Round 7
// 221.151 us; speedup vs baseline: 1.6096x; 1.0162x over previous
//
#include <hip/hip_runtime.h>
#include <math.h>

#define NPOS 2048   // n
#define MFFT 4096   // 2n
#define NH 8        // heads
#define PDW 16      // pos_dim
#define NE 64       // E
#define NB 16       // batch

// native 2-wide float vector -> compiler emits v_pk_*_f32 packed math
typedef float v2f __attribute__((ext_vector_type(2)));

// rot<SGN>(z): SGN=-1 -> -i*z = (z.y, -z.x); SGN=+1 -> +i*z = (-z.y, z.x)
template <int SGN>
__device__ __forceinline__ v2f rot(v2f z) {
    return (SGN < 0) ? (v2f){z.y, -z.x} : (v2f){-z.y, z.x};
}

__device__ __forceinline__ v2f cmul(v2f a, v2f b) {
    // (ax*bx - ay*by, ax*by + ay*bx) = a.xx*b + a.yy*(-b.y, b.x)
    return a.xx * b + a.yy * (v2f){-b.y, b.x};
}

// Wave-local LDS fence: orders this wave's ds_write -> ds_read (DS ops of a
// wave complete in issue order; lgkmcnt(0) + memory clobber stops compiler
// reordering). Valid ONLY when producer and consumer are the same wave.
__device__ __forceinline__ void wave_fence() {
    __builtin_amdgcn_sched_barrier(0);
    asm volatile("s_waitcnt lgkmcnt(0)" ::: "memory");
    __builtin_amdgcn_sched_barrier(0);
}

// LDS swizzle: base-8 digits d0^=d1, d1^=d2. Bijective; every stage's wave
// access is exactly 2-way bank aliasing (free). Only mixes d0,d1 -> keeps
// each 512-element chunk (d3 fixed) intact, so stages 2-4 stay wave-local.
__device__ __forceinline__ int swz(int a) {
    return a ^ ((a >> 3) & 7) ^ (((a >> 6) & 7) << 3);
}

// 8-point DFT, natural in -> natural out. SGN=-1 fwd, +1 inv (no 1/8 scale).
// MODE: 0 full; 1 = inputs v[4..7] are zero; 2 = only outputs v[0..3] needed.
template <int SGN, int MODE>
__device__ __forceinline__ void dft8(v2f v[8]) {
    const float c = 0.70710678118654757f;
    v2f E0, E1, E2, E3, O0, O1, O2, O3;
    if (MODE == 1) {
        v2f a = v[0], b = v[2];
        E0 = a + b; E2 = a - b; E1 = a + rot<SGN>(b); E3 = a - rot<SGN>(b);
        a = v[1]; b = v[3];
        O0 = a + b; O2 = a - b; O1 = a + rot<SGN>(b); O3 = a - rot<SGN>(b);
    } else {
        v2f t0 = v[0] + v[4], t1 = v[0] - v[4];
        v2f t2 = v[2] + v[6], t3 = v[2] - v[6];
        E0 = t0 + t2; E2 = t0 - t2;
        E1 = t1 + rot<SGN>(t3); E3 = t1 - rot<SGN>(t3);
        t0 = v[1] + v[5]; t1 = v[1] - v[5];
        t2 = v[3] + v[7]; t3 = v[3] - v[7];
        O0 = t0 + t2; O2 = t0 - t2;
        O1 = t1 + rot<SGN>(t3); O3 = t1 - rot<SGN>(t3);
    }
    // W8^k * O[k]: W8^1*z = c*(z + rot(z)), W8^2*z = rot(z), W8^3*z = c*(rot(z) - z)
    v2f w1O = c * (O1 + rot<SGN>(O1));
    v2f w2O = rot<SGN>(O2);
    v2f w3O = c * (rot<SGN>(O3) - O3);
    v[0] = E0 + O0; v[1] = E1 + w1O; v[2] = E2 + w2O; v[3] = E3 + w3O;
    if (MODE != 2) {
        v[4] = E0 - O0; v[5] = E1 - w1O; v[6] = E2 - w2O; v[7] = E3 - w3O;
    }
}

// u[j] *= e^{i ang j}, j=1..7 (balanced tree, depth 3)
__device__ __forceinline__ void twiddle8(v2f u[8], float ang) {
    float sn, cs;
    __sincosf(ang, &sn, &cs);
    v2f w1 = (v2f){cs, sn};
    v2f w2 = cmul(w1, w1), w3 = cmul(w1, w2), w4 = cmul(w2, w2);
    v2f w5 = cmul(w2, w3), w6 = cmul(w3, w3), w7 = cmul(w3, w4);
    u[1] = cmul(u[1], w1); u[2] = cmul(u[2], w2); u[3] = cmul(u[3], w3);
    u[4] = cmul(u[4], w4); u[5] = cmul(u[5], w5); u[6] = cmul(u[6], w6);
    u[7] = cmul(u[7], w7);
}

#define A4096 1.5339807878856412e-3f   // 2pi/4096
#define A512  1.2271846303085130e-2f   // 2pi/512
#define A64   9.8174770424681035e-2f   // 2pi/64

// Forward 4096-pt FFT, radix-8 DIF, 512 threads, in-place swizzled LDS.
// In: v[r] = x[m + 512 r] natural. Out: v[j] = bin pi(8 m + j).
// Stage-1 exchange is cross-wave (full barrier); stages 2-4 are each
// confined to one wave's 512-element chunk (wave fences only).
template <int MODE1>
__device__ __forceinline__ void fftR8_fwd(v2f v[8], v2f* sh, int m) {
    dft8<-1, MODE1>(v);
    twiddle8(v, -A4096 * (float)m);
    #pragma unroll
    for (int j = 0; j < 8; ++j) sh[swz(m + 512 * j)] = v[j];
    __syncthreads();                                   // cross-wave exchange
    int t2 = m & 63, b2 = (m >> 6) << 9;
    #pragma unroll
    for (int r = 0; r < 8; ++r) v[r] = sh[swz(b2 + t2 + 64 * r)];
    dft8<-1, 0>(v);
    twiddle8(v, -A512 * (float)t2);
    #pragma unroll
    for (int j = 0; j < 8; ++j) sh[swz(b2 + t2 + 64 * j)] = v[j];
    wave_fence();                                      // wave-local
    int t3 = m & 7, b3 = (m >> 3) << 6;
    #pragma unroll
    for (int r = 0; r < 8; ++r) v[r] = sh[swz(b3 + t3 + 8 * r)];
    dft8<-1, 0>(v);
    twiddle8(v, -A64 * (float)t3);
    #pragma unroll
    for (int j = 0; j < 8; ++j) sh[swz(b3 + t3 + 8 * j)] = v[j];
    wave_fence();                                      // wave-local
    int b4 = m << 3;
    #pragma unroll
    for (int r = 0; r < 8; ++r) v[r] = sh[swz(b4 + r)];
    dft8<-1, 0>(v);
}

#define LN_RELU(G, Bv)                                                        \
    {                                                                         \
        float mu = 0.f;                                                       \
        _Pragma("unroll") for (int i = 0; i < PDW; ++i) mu += h[i];           \
        mu *= (1.0f / PDW);                                                   \
        float var = 0.f;                                                      \
        _Pragma("unroll") for (int i = 0; i < PDW; ++i) {                     \
            float d = h[i] - mu;                                              \
            var += d * d;                                                     \
        }                                                                     \
        var *= (1.0f / PDW);                                                  \
        float inv = 1.0f / sqrtf(var + 1e-5f);                                \
        _Pragma("unroll") for (int i = 0; i < PDW; ++i) {                     \
            float nv = (h[i] - mu) * inv * G[i] + Bv[i];                      \
            r[i] = fmaxf(nv, 0.f);                                            \
        }                                                                     \
    }

// One thread per (position, head): 16384 threads / 64 blocks.
__global__ __launch_bounds__(256) void dpb_mlp_kernel(
    const float* __restrict__ w0, const float* __restrict__ b0,
    const float* __restrict__ g1, const float* __restrict__ gb1,
    const float* __restrict__ w1, const float* __restrict__ b1,
    const float* __restrict__ g2, const float* __restrict__ gb2,
    const float* __restrict__ w2, const float* __restrict__ b2,
    const float* __restrict__ g3, const float* __restrict__ gb3,
    const float* __restrict__ w3, const float* __restrict__ b3,
    float* __restrict__ dpbout)
{
    int idx = blockIdx.x * 256 + threadIdx.x;   // idx = p*8 + h
    int hh = idx & 7;
    float t = (float)(idx >> 3);
    float h[PDW], r[PDW];
    #pragma unroll
    for (int i = 0; i < PDW; ++i) h[i] = t * w0[i] + b0[i];
    LN_RELU(g1, gb1);
    #pragma unroll
    for (int j = 0; j < PDW; ++j) {
        float acc = b1[j];
        #pragma unroll
        for (int i = 0; i < PDW; ++i) acc += r[i] * w1[i * PDW + j];
        h[j] = acc;
    }
    LN_RELU(g2, gb2);
    #pragma unroll
    for (int j = 0; j < PDW; ++j) {
        float acc = b2[j];
        #pragma unroll
        for (int i = 0; i < PDW; ++i) acc += r[i] * w2[i * PDW + j];
        h[j] = acc;
    }
    LN_RELU(g3, gb3);
    float acc = b3[hh];
    #pragma unroll
    for (int i = 0; i < PDW; ++i) acc += r[i] * w3[i * NH + hh];
    dpbout[idx] = acc;
}

// One block per head, 512 threads: build a[h], fwd FFT, store V in the
// register-order layout V[h][8m + j] (1/M folded in).
__global__ __launch_bounds__(512) void toeplitz_fft_kernel(
    const float* __restrict__ gamma, const float* __restrict__ dpbout,
    v2f* __restrict__ V)
{
    __shared__ v2f sh[MFFT];
    int hh = blockIdx.x;
    int m = threadIdx.x;
    float lsg = -log1pf(__expf(-gamma[0]));  // log(sigmoid(gamma))
    v2f v[8];
    #pragma unroll
    for (int r = 0; r < 8; ++r) {
        int k = m + 512 * r;
        float val;
        if (k == 0 || k == NPOS)  val = dpbout[hh];                       // zero_dpb
        else if (k < NPOS)        val = lsg * (float)k + dpbout[k * NH + hh];
        else                      val = lsg * (float)(2 * NPOS - k) + dpbout[(k - NPOS) * NH + hh];
        val = fminf(30.f, fmaxf(-60.f, val));
        v[r] = (v2f){__expf(val) * (1.0f / (float)MFFT), 0.f};
    }
    fftR8_fwd<0>(v, sh, m);
    #pragma unroll
    for (int j = 0; j < 8; ++j) V[hh * MFFT + 8 * m + j] = v[j];
}

// One block per (b,h,e-pair), 512 threads x 8 v2f. XCD-grouped: all 32
// pair-blocks of one (b,h) on the same XCD (head == XCD, V[h] L2-resident).
__global__ __launch_bounds__(512) void conv_kernel(
    const float* __restrict__ x, const v2f* __restrict__ V,
    float* __restrict__ out)
{
    __shared__ v2f sh[MFFT];
    int wg = blockIdx.x;
    int xcd = wg & 7;
    int slot = wg >> 3;
    int pair = slot & 31;
    int bh = ((slot >> 5) << 3) | xcd;
    int h = bh & (NH - 1);
    int m = threadIdx.x;

    const float* xp = x + (size_t)bh * NPOS * NE + pair * 2;
    v2f v[8];
    #pragma unroll
    for (int r = 0; r < 4; ++r)
        v[r] = *reinterpret_cast<const v2f*>(xp + (size_t)(m + 512 * r) * NE);
    #pragma unroll
    for (int r = 4; r < 8; ++r) v[r] = (v2f){0.f, 0.f};

    fftR8_fwd<1>(v, sh, m);

    int b4 = m << 3;
    const v2f* Vh = V + h * MFFT + b4;
    #pragma unroll
    for (int j = 0; j < 8; ++j) v[j] = cmul(v[j], Vh[j]);

    // ---- inverse: exact stage-mirror, conjugate twiddles.
    // inv stages 1-3 are wave-local (own 512-chunk); only the final
    // stride-512 exchange is cross-wave.
    dft8<1, 0>(v);
    #pragma unroll
    for (int r = 0; r < 8; ++r) sh[swz(b4 + r)] = v[r];
    wave_fence();                                      // wave-local
    int t3 = m & 7, b3 = (m >> 3) << 6;
    #pragma unroll
    for (int j = 0; j < 8; ++j) v[j] = sh[swz(b3 + t3 + 8 * j)];
    twiddle8(v, A64 * (float)t3);
    dft8<1, 0>(v);
    #pragma unroll
    for (int r = 0; r < 8; ++r) sh[swz(b3 + t3 + 8 * r)] = v[r];
    wave_fence();                                      // wave-local
    int t2 = m & 63, b2 = (m >> 6) << 9;
    #pragma unroll
    for (int j = 0; j < 8; ++j) v[j] = sh[swz(b2 + t2 + 64 * j)];
    twiddle8(v, A512 * (float)t2);
    dft8<1, 0>(v);
    #pragma unroll
    for (int r = 0; r < 8; ++r) sh[swz(b2 + t2 + 64 * r)] = v[r];
    __syncthreads();                                   // cross-wave exchange
    #pragma unroll
    for (int j = 0; j < 8; ++j) v[j] = sh[swz(m + 512 * j)];
    twiddle8(v, A4096 * (float)m);
    dft8<1, 2>(v);   // only v[0..3] needed (rows 0..2047)

    float* op = out + (size_t)bh * NPOS * NE + pair * 2;
    #pragma unroll
    for (int r = 0; r < 4; ++r)
        *reinterpret_cast<v2f*>(op + (size_t)(m + 512 * r) * NE) = v[r];
}

extern "C" void kernel_launch(void* const* d_in, const int* in_sizes, int n_in,
                              void* d_out, int out_size, void* d_ws, size_t ws_size,
                              hipStream_t stream) {
    const float* x     = (const float*)d_in[0];
    const float* gamma = (const float*)d_in[1];
    const float* w0    = (const float*)d_in[2];
    const float* b0    = (const float*)d_in[3];
    const float* g1    = (const float*)d_in[4];
    const float* gb1   = (const float*)d_in[5];
    const float* w1    = (const float*)d_in[6];
    const float* b1    = (const float*)d_in[7];
    const float* g2    = (const float*)d_in[8];
    const float* gb2   = (const float*)d_in[9];
    const float* w2    = (const float*)d_in[10];
    const float* b2    = (const float*)d_in[11];
    const float* g3    = (const float*)d_in[12];
    const float* gb3   = (const float*)d_in[13];
    const float* w3    = (const float*)d_in[14];
    const float* b3    = (const float*)d_in[15];
    float* out = (float*)d_out;

    float* dpbout = (float*)d_ws;                  // 2048*8 fp32 = 64 KB
    v2f*   V      = (v2f*)((char*)d_ws + 65536);   // 8*4096 v2f = 256 KB

    dpb_mlp_kernel<<<NPOS * NH / 256, 256, 0, stream>>>(w0, b0, g1, gb1, w1, b1,
                                                        g2, gb2, w2, b2, g3, gb3,
                                                        w3, b3, dpbout);
    toeplitz_fft_kernel<<<NH, 512, 0, stream>>>(gamma, dpbout, V);
    conv_kernel<<<NB * NH * 32, 512, 0, stream>>>(x, V, out);
}